// Round 1
// baseline (884.178 us; speedup 1.0000x reference)
//
#include <hip/hip_runtime.h>

#define NN 20000
#define NEIGH 12
#define HD 64
#define NW 256          // 4*HD: [rel0 | rel1 | rel2 | root]
#define KB 480          // bond feature width  (12*40)
#define KA 2880         // angle feature width (144*20)
#define NCRYS 20
#define ADJ_CAP 64

// ---------------- weight packing: Wp[k][r*64+h] ----------------
__global__ void pack_kernel(const float* __restrict__ Wrel, const float* __restrict__ Wroot,
                            float* __restrict__ Wp, int K) {
    int total = K * NW;
    for (int idx = blockIdx.x * blockDim.x + threadIdx.x; idx < total;
         idx += gridDim.x * blockDim.x) {
        int k = idx >> 8;
        int c = idx & 255;
        int r = c >> 6;
        int h = c & 63;
        Wp[idx] = (r < 3) ? Wrel[(r * K + k) * HD + h] : Wroot[k * HD + h];
    }
}

// ---------------- reverse adjacency build (once; reused by all 4 layers) ----------------
__global__ void build_adj_kernel(const int* __restrict__ species, const int* __restrict__ nbr,
                                 int* __restrict__ adj, int* __restrict__ deg) {
    int e = blockIdx.x * blockDim.x + threadIdx.x;
    if (e >= NN * NEIGH) return;
    int i = e / NEIGH;      // src node
    int d = nbr[e];         // dst node
    int r = species[i] + species[d];   // etype in {0,1,2}
    int slot = atomicAdd(&deg[d], 1);
    if (slot < ADJ_CAP) adj[d * ADJ_CAP + slot] = i | (r << 28);
}

// ---------------- fused GEMM: Y[m][c] = sum_k x[m][k] * Wp[k][c] ----------------
// MODE 0: x = gbf(bond_fea)  on the fly, KTOT=480,  KT=40
// MODE 1: x = gbf(angle_fea) on the fly, KTOT=2880, KT=40
// MODE 2: x = dense H matrix (N,64),     KTOT=64,   KT=32
template <int MODE, int KTOT, int KT>
__global__ __launch_bounds__(256, 2) void gemm_kernel(const float* __restrict__ xraw,
                                                      const float* __restrict__ W,
                                                      float* __restrict__ Y) {
    __shared__ __align__(16) float wt[KT * NW];
    __shared__ __align__(16) float xt[32 * KT];
    const int tid = threadIdx.x;
    const int tc = tid & 63;   // column group: cols tc*4 .. tc*4+3
    const int tw = tid >> 6;   // wave id: rows tw*8 .. tw*8+7
    const int m0 = blockIdx.x * 32;

    float acc[8][4];
#pragma unroll
    for (int i = 0; i < 8; i++)
#pragma unroll
        for (int j = 0; j < 4; j++) acc[i][j] = 0.f;

    for (int kt0 = 0; kt0 < KTOT; kt0 += KT) {
        __syncthreads();
        // --- stage W tile (KT x 256) ---
        {
            const float4* wg = (const float4*)(W + (size_t)kt0 * NW);
            float4* ws4 = (float4*)wt;
#pragma unroll
            for (int i = 0; i < (KT * NW / 4) / 256; i++) {
                int idx = i * 256 + tid;
                ws4[idx] = wg[idx];
            }
        }
        // --- stage x tile (32 x KT), fusing the gaussian basis expansion ---
#pragma unroll
        for (int i = 0; i < (32 * KT) / 256; i++) {
            int idx = i * 256 + tid;
            int mm = idx / KT;
            int kk = idx - mm * KT;
            int k = kt0 + kk;
            float v;
            if (MODE == 0) {
                int j = k / 40, s = k - j * 40;
                float a = xraw[(size_t)(m0 + mm) * NEIGH + j];
                float f = (float)s * (8.0f / 39.0f);
                float d = a - f;
                v = __expf(-d * d * 25.0f);          // gamma = 0.2
            } else if (MODE == 1) {
                int j = k / 20, s = k - j * 20;
                float a = xraw[(size_t)(m0 + mm) * 144 + j];
                float f = -1.0f + (float)s * (2.0f / 19.0f);
                float d = a - f;
                v = __expf(-d * d * 100.0f);         // gamma = 0.1
            } else {
                v = xraw[(size_t)(m0 + mm) * HD + k];
            }
            xt[mm * KT + kk] = v;
        }
        __syncthreads();
        // --- compute: per thread 8 rows x 4 cols; x reads are wave-broadcast ---
#pragma unroll
        for (int k4 = 0; k4 < KT; k4 += 4) {
            float4 wv[4];
#pragma unroll
            for (int kk = 0; kk < 4; kk++)
                wv[kk] = *(const float4*)&wt[(k4 + kk) * NW + tc * 4];
#pragma unroll
            for (int rr = 0; rr < 8; rr++) {
                float4 xv = *(const float4*)&xt[(tw * 8 + rr) * KT + k4];
                acc[rr][0] += xv.x * wv[0].x;
                acc[rr][1] += xv.x * wv[0].y;
                acc[rr][2] += xv.x * wv[0].z;
                acc[rr][3] += xv.x * wv[0].w;
                acc[rr][0] += xv.y * wv[1].x;
                acc[rr][1] += xv.y * wv[1].y;
                acc[rr][2] += xv.y * wv[1].z;
                acc[rr][3] += xv.y * wv[1].w;
                acc[rr][0] += xv.z * wv[2].x;
                acc[rr][1] += xv.z * wv[2].y;
                acc[rr][2] += xv.z * wv[2].z;
                acc[rr][3] += xv.z * wv[2].w;
                acc[rr][0] += xv.w * wv[3].x;
                acc[rr][1] += xv.w * wv[3].y;
                acc[rr][2] += xv.w * wv[3].z;
                acc[rr][3] += xv.w * wv[3].w;
            }
        }
    }
    // --- store ---
#pragma unroll
    for (int rr = 0; rr < 8; rr++) {
        int m = m0 + tw * 8 + rr;
        float4 o = make_float4(acc[rr][0], acc[rr][1], acc[rr][2], acc[rr][3]);
        *(float4*)&Y[(size_t)m * NW + tc * 4] = o;
    }
}

// ---------------- aggregation: out = relu(root + b + sum_r S_r / max(c_r,1)) ----------------
__global__ __launch_bounds__(256) void agg_kernel(const float* __restrict__ Y,
                                                  const int* __restrict__ adj,
                                                  const int* __restrict__ deg,
                                                  const float* __restrict__ bias,
                                                  float* __restrict__ out) {
    int node = blockIdx.x * 4 + (threadIdx.x >> 6);  // one wave per node
    int h = threadIdx.x & 63;
    if (node >= NN) return;
    float s0 = 0.f, s1 = 0.f, s2 = 0.f;
    int c0 = 0, c1 = 0, c2 = 0;
    int dg = deg[node];
    if (dg > ADJ_CAP) dg = ADJ_CAP;
    const int* al = adj + (size_t)node * ADJ_CAP;
    for (int k = 0; k < dg; k++) {
        int e = al[k];                 // broadcast read
        int src = e & 0x0FFFFFFF;
        int r = e >> 28;
        float v = Y[(size_t)src * NW + r * 64 + h];  // coalesced 256B row gather
        if (r == 0) { s0 += v; c0++; }
        else if (r == 1) { s1 += v; c1++; }
        else { s2 += v; c2++; }
    }
    float o = Y[(size_t)node * NW + 192 + h] + bias[h] +
              s0 / fmaxf((float)c0, 1.f) + s1 / fmaxf((float)c1, 1.f) +
              s2 / fmaxf((float)c2, 1.f);
    out[(size_t)node * HD + h] = fmaxf(o, 0.f);
}

// ---------------- crystal pooling (partial sums, 8 chunks per crystal) ----------------
__global__ void pool_kernel(const float* __restrict__ Hb, const float* __restrict__ Ha,
                            const int* __restrict__ crys, float* __restrict__ pooled) {
    int c = blockIdx.x >> 3;
    int chunk = blockIdx.x & 7;
    int f = threadIdx.x;  // 0..127
    int start = crys[c * 2];
    int end = (c < NCRYS - 1) ? crys[(c + 1) * 2] : NN;  // searchsorted boundary
    int len = end - start;
    int per = (len + 7) / 8;
    int s0 = start + chunk * per;
    int e0 = s0 + per;
    if (e0 > end) e0 = end;
    float acc = 0.f;
    for (int i = s0; i < e0; i++)
        acc += (f < 64) ? Hb[(size_t)i * HD + f] : Ha[(size_t)i * HD + (f - 64)];
    atomicAdd(&pooled[c * 128 + f], acc);
}

// ---------------- final: out = (pooled/count) @ fc_W + fc_b ----------------
__global__ void final_kernel(const float* __restrict__ pooled, const int* __restrict__ crys,
                             const float* __restrict__ fcW, const float* __restrict__ fcb,
                             float* __restrict__ out) {
    int t = threadIdx.x;
    if (t < NCRYS * 2) {
        int c = t >> 1;
        int o = t & 1;
        float cnt = (float)(crys[c * 2 + 1] - crys[c * 2]);
        float acc = fcb[o];
        for (int k = 0; k < 128; k++) acc += (pooled[c * 128 + k] / cnt) * fcW[k * 2 + o];
        out[t] = acc;
    }
}

extern "C" void kernel_launch(void* const* d_in, const int* in_sizes, int n_in,
                              void* d_out, int out_size, void* d_ws, size_t ws_size,
                              hipStream_t stream) {
    const float* bond    = (const float*)d_in[0];
    const float* angle   = (const float*)d_in[1];
    const int*   species = (const int*)d_in[2];
    const int*   nbr     = (const int*)d_in[3];
    const int*   crys    = (const int*)d_in[4];
    const float* W1b_rel = (const float*)d_in[5];
    const float* W1b_root= (const float*)d_in[6];
    const float* b1b     = (const float*)d_in[7];
    const float* W1a_rel = (const float*)d_in[8];
    const float* W1a_root= (const float*)d_in[9];
    const float* b1a     = (const float*)d_in[10];
    const float* W2b_rel = (const float*)d_in[11];
    const float* W2b_root= (const float*)d_in[12];
    const float* b2b     = (const float*)d_in[13];
    const float* W2a_rel = (const float*)d_in[14];
    const float* W2a_root= (const float*)d_in[15];
    const float* b2a     = (const float*)d_in[16];
    const float* fcW     = (const float*)d_in[17];
    const float* fcb     = (const float*)d_in[18];
    float* out = (float*)d_out;

    char* ws = (char*)d_ws;
    size_t off = 0;
    auto alloc = [&](size_t bytes) {
        char* p = ws + off;
        off = (off + bytes + 255) & ~(size_t)255;
        return p;
    };
    float* Wp1b  = (float*)alloc((size_t)KB * NW * 4);
    float* Wp1a  = (float*)alloc((size_t)KA * NW * 4);
    float* Wp2b  = (float*)alloc((size_t)HD * NW * 4);
    float* Wp2a  = (float*)alloc((size_t)HD * NW * 4);
    float* Y     = (float*)alloc((size_t)NN * NW * 4);
    float* Hb    = (float*)alloc((size_t)NN * HD * 4);
    float* Ha    = (float*)alloc((size_t)NN * HD * 4);
    float* Hb2   = (float*)alloc((size_t)NN * HD * 4);
    float* Ha2   = (float*)alloc((size_t)NN * HD * 4);
    int*   adj   = (int*)alloc((size_t)NN * ADJ_CAP * 4);
    int*   deg   = (int*)alloc((size_t)NN * 4);
    float* pooled= (float*)alloc((size_t)NCRYS * 128 * 4);

    hipMemsetAsync(deg, 0, (size_t)NN * 4, stream);
    hipMemsetAsync(pooled, 0, (size_t)NCRYS * 128 * 4, stream);

    pack_kernel<<<512, 256, 0, stream>>>(W1b_rel, W1b_root, Wp1b, KB);
    pack_kernel<<<512, 256, 0, stream>>>(W1a_rel, W1a_root, Wp1a, KA);
    pack_kernel<<<64, 256, 0, stream>>>(W2b_rel, W2b_root, Wp2b, HD);
    pack_kernel<<<64, 256, 0, stream>>>(W2a_rel, W2a_root, Wp2a, HD);
    build_adj_kernel<<<(NN * NEIGH + 255) / 256, 256, 0, stream>>>(species, nbr, adj, deg);

    // layer 1 bond
    gemm_kernel<0, KB, 40><<<NN / 32, 256, 0, stream>>>(bond, Wp1b, Y);
    agg_kernel<<<NN / 4, 256, 0, stream>>>(Y, adj, deg, b1b, Hb);
    // layer 1 angle
    gemm_kernel<1, KA, 40><<<NN / 32, 256, 0, stream>>>(angle, Wp1a, Y);
    agg_kernel<<<NN / 4, 256, 0, stream>>>(Y, adj, deg, b1a, Ha);
    // layer 2 bond
    gemm_kernel<2, HD, 32><<<NN / 32, 256, 0, stream>>>(Hb, Wp2b, Y);
    agg_kernel<<<NN / 4, 256, 0, stream>>>(Y, adj, deg, b2b, Hb2);
    // layer 2 angle
    gemm_kernel<2, HD, 32><<<NN / 32, 256, 0, stream>>>(Ha, Wp2a, Y);
    agg_kernel<<<NN / 4, 256, 0, stream>>>(Y, adj, deg, b2a, Ha2);

    pool_kernel<<<NCRYS * 8, 128, 0, stream>>>(Hb2, Ha2, crys, pooled);
    final_kernel<<<1, 64, 0, stream>>>(pooled, crys, fcW, fcb, out);
}

// Round 2
// 381.186 us; speedup vs baseline: 2.3195x; 2.3195x over previous
//
#include <hip/hip_runtime.h>

#define NN 20000
#define NEIGH 12
#define NCRYS 20
#define MT2 1256   // padded M row-tiles of 16: 157*8 (20096 rows)

typedef __bf16 bf16x8 __attribute__((ext_vector_type(8)));
typedef float f32x4 __attribute__((ext_vector_type(4)));

// ============================================================
// Weight pack: W[k][n] (n = r*64+h, r=3 -> root) -> bf16 MFMA-B frag layout
// Wp[kt][nt][k8][ni][j] : kt=k/32, k8=(k%32)/8, j=k%8, nt=n/16, ni=n%16
// ============================================================
__global__ void pack_w(const float* __restrict__ Wrel, const float* __restrict__ Wroot,
                       __bf16* __restrict__ Wp, int K) {
    int total = K * 256;
    for (int idx = blockIdx.x * blockDim.x + threadIdx.x; idx < total;
         idx += gridDim.x * blockDim.x) {
        int k = idx >> 8, n = idx & 255;
        int r = n >> 6, h = n & 63;
        float v = (r < 3) ? Wrel[((size_t)r * K + k) * 64 + h] : Wroot[(size_t)k * 64 + h];
        int kt = k >> 5, k8 = (k >> 3) & 3, j = k & 7, nt = n >> 4, ni = n & 15;
        Wp[((((size_t)kt * 16 + nt) * 4 + k8) * 16 + ni) * 8 + j] = (__bf16)v;
    }
}

// ============================================================
// Reverse adjacency (fixed across layers)
// ============================================================
__global__ void build_adj_kernel(const int* __restrict__ species, const int* __restrict__ nbr,
                                 int* __restrict__ adj, int* __restrict__ deg) {
    int e = blockIdx.x * blockDim.x + threadIdx.x;
    if (e >= NN * NEIGH) return;
    int i = e / NEIGH;
    int d = nbr[e];
    int r = species[i] + species[d];
    int slot = atomicAdd(&deg[d], 1);
    if (slot < 64) adj[(size_t)d * 64 + slot] = i | (r << 28);
}

// ============================================================
// MFMA GEMM: Y[20000][256] = X[20000][K] @ Wp
// MODE 0: X = gbf(bond), K=480   MODE 1: X = gbf(angle), K=2880
// MODE 2: X = packed bf16 H (from agg), K=64
// block tile 128x128 (grid 157 x 2), 4 waves each 64x64 (4x4 tiles of 16x16)
// ============================================================
template <int MODE, int KTOT>
__global__ __launch_bounds__(256) void gemm_mfma(const float* __restrict__ xraw,
                                                 const __bf16* __restrict__ Ap,
                                                 const __bf16* __restrict__ Wp,
                                                 float* __restrict__ Y) {
    constexpr int NKT = KTOT / 32;
    __shared__ __align__(16) __bf16 Al[4096];  // [mt8][k8 4][mi 16][j 8]
    __shared__ __align__(16) __bf16 Bl[4096];  // [nt8][k8 4][ni 16][j 8]
    const int tid = threadIdx.x;
    const int lane = tid & 63, wv = tid >> 6;
    const int mb = blockIdx.x, nb = blockIdx.y;
    const int m0 = mb * 128;
    const int rw = wv & 1, cw = wv >> 1;

    f32x4 acc[4][4] = {};

    for (int kt = 0; kt < NKT; ++kt) {
        __syncthreads();
        // ---- stage B tile: 8 KB contiguous, pre-packed frag layout ----
        {
            const float4* src = (const float4*)(Wp + (((size_t)kt * 16 + nb * 8) << 9));
            float4* dst = (float4*)Bl;
            float4 v0 = src[tid];
            float4 v1 = src[tid + 256];
            dst[tid] = v0;
            dst[tid + 256] = v1;
        }
        if constexpr (MODE == 2) {
            const float4* src = (const float4*)(Ap + (((size_t)kt * MT2 + mb * 8) << 9));
            float4* dst = (float4*)Al;
            float4 v0 = src[tid];
            float4 v1 = src[tid + 256];
            dst[tid] = v0;
            dst[tid + 256] = v1;
        } else {
            // ---- fused gbf staging: compute 8 bf16 per combo, ds_write_b128 ----
            const int DIVN = (MODE == 0) ? 40 : 20;
            const int RWID = (MODE == 0) ? NEIGH : 144;
            const float F0 = (MODE == 0) ? 0.f : -1.f;
            const float FS = (MODE == 0) ? (8.f / 39.f) : (2.f / 19.f);
            const float GAM = (MODE == 0) ? 25.f : 100.f;
#pragma unroll
            for (int c2 = 0; c2 < 2; ++c2) {
                int c = tid + c2 * 256;            // micro-tile combo 0..511
                int mt = c >> 6, k8 = (c >> 4) & 3, mi = c & 15;
                int mloc = mt * 16 + mi;
                int m = m0 + mloc;
                int kb = kt * 32 + k8 * 8;
                const float* rowp = xraw + (size_t)m * RWID;
                int jrA = kb / DIVN;
                int jrB = (kb + 7) / DIVN;
                bool mv = m < NN;
                float a0 = mv ? rowp[jrA] : 0.f;
                float a1 = (mv && jrB != jrA) ? rowp[jrB] : a0;
                bf16x8 vals;
#pragma unroll
                for (int j = 0; j < 8; ++j) {
                    int k = kb + j;
                    int jr = k / DIVN;
                    int s = k - jr * DIVN;
                    float a = (jr == jrA) ? a0 : a1;
                    float d = a - (F0 + (float)s * FS);
                    vals[j] = (__bf16)__expf(-d * d * GAM);
                }
                *(bf16x8*)&Al[(size_t)c << 3] = vals;
            }
        }
        __syncthreads();
        // ---- frag reads (contiguous 1KB b128 per frag) + 16 MFMA ----
        bf16x8 af[4], bfr[4];
        int fro = ((lane >> 4) << 4) + (lane & 15);  // k8*16 + ni(=mi)
#pragma unroll
        for (int t4 = 0; t4 < 4; ++t4) {
            af[t4] = *(const bf16x8*)&Al[((((rw * 4 + t4) << 6) + fro) << 3)];
            bfr[t4] = *(const bf16x8*)&Bl[((((cw * 4 + t4) << 6) + fro) << 3)];
        }
#pragma unroll
        for (int i = 0; i < 4; ++i)
#pragma unroll
            for (int j = 0; j < 4; ++j)
                acc[i][j] = __builtin_amdgcn_mfma_f32_16x16x32_bf16(af[i], bfr[j], acc[i][j], 0, 0, 0);
    }

    // ---- epilogue: C/D layout col=lane&15, row=(lane>>4)*4+reg ----
    const int n0 = nb * 128 + cw * 64;
    const int mrow0 = m0 + rw * 64 + ((lane >> 4) << 2);
    const int ncol = n0 + (lane & 15);
    if (m0 + 128 <= NN) {
#pragma unroll
        for (int i = 0; i < 4; ++i)
#pragma unroll
            for (int j = 0; j < 4; ++j)
#pragma unroll
                for (int v = 0; v < 4; ++v)
                    Y[(size_t)(mrow0 + i * 16 + v) * 256 + ncol + j * 16] = acc[i][j][v];
    } else {
#pragma unroll
        for (int i = 0; i < 4; ++i)
#pragma unroll
            for (int j = 0; j < 4; ++j)
#pragma unroll
                for (int v = 0; v < 4; ++v) {
                    int m = mrow0 + i * 16 + v;
                    if (m < NN) Y[(size_t)m * 256 + ncol + j * 16] = acc[i][j][v];
                }
    }
}

// ============================================================
// Aggregation: out = relu(root + b + sum_r mean_r(msg))
// one wave per node; all adjacency in one coalesced 256B read + shfl
// OUT_PACKED=1: write bf16 packed-A frag layout (feeds dense GEMM), covers pad rows
// OUT_PACKED=0: write f32 [node][64] (feeds pooling)
// ============================================================
template <int OUT_PACKED>
__global__ __launch_bounds__(256) void agg2(const float* __restrict__ Y,
                                            const int* __restrict__ adj,
                                            const int* __restrict__ deg,
                                            const float* __restrict__ bias,
                                            void* __restrict__ outp) {
    int node = blockIdx.x * 4 + (threadIdx.x >> 6);
    int h = threadIdx.x & 63;
    float o = 0.f;
    if (node < NN) {
        int dg = min(deg[node], 64);
        int e = adj[(size_t)node * 64 + h];  // coalesced; lane h holds edge h
        bool val = h < dg;
        int r = e >> 28;
        unsigned long long bl0 = __ballot(val && r == 0);
        unsigned long long bl1 = __ballot(val && r == 1);
        unsigned long long bl2 = __ballot(val && r == 2);
        int c0 = __popcll(bl0), c1 = __popcll(bl1), c2 = __popcll(bl2);
        float s0 = 0.f, s1 = 0.f, s2 = 0.f;
        for (int k = 0; k < dg; k += 4) {
            float v[4];
            int rr[4];
#pragma unroll
            for (int i = 0; i < 4; ++i) {
                int kk = k + i;
                int ek = __shfl(e, kk);
                int src = ek & 0x0FFFFFFF;
                rr[i] = ek >> 28;
                v[i] = (kk < dg) ? Y[(size_t)src * 256 + rr[i] * 64 + h] : 0.f;
            }
#pragma unroll
            for (int i = 0; i < 4; ++i) {
                if (k + i < dg) {  // wave-uniform
                    if (rr[i] == 0) s0 += v[i];
                    else if (rr[i] == 1) s1 += v[i];
                    else s2 += v[i];
                }
            }
        }
        o = Y[(size_t)node * 256 + 192 + h] + bias[h] +
            s0 / fmaxf((float)c0, 1.f) + s1 / fmaxf((float)c1, 1.f) +
            s2 / fmaxf((float)c2, 1.f);
        o = fmaxf(o, 0.f);
    }
    if constexpr (OUT_PACKED) {
        // packed-A layout: [kt][mt][k8][mi][j]; node->mt,mi; h->kt,k8,j
        int mt = node >> 4, mi = node & 15;
        int ktt = h >> 5, k8 = (h >> 3) & 3, j = h & 7;
        ((__bf16*)outp)[((((size_t)ktt * MT2 + mt) * 4 + k8) * 16 + mi) * 8 + j] = (__bf16)o;
    } else {
        if (node < NN) ((float*)outp)[(size_t)node * 64 + h] = o;
    }
}

// ============================================================
// Crystal pooling: 64 chunks per crystal, partial sums via atomics
// ============================================================
__global__ void pool_kernel(const float* __restrict__ Hb, const float* __restrict__ Ha,
                            const int* __restrict__ crys, float* __restrict__ pooled) {
    int c = blockIdx.x >> 6;
    int chunk = blockIdx.x & 63;
    int f = threadIdx.x;  // 0..127
    int start = crys[c * 2];
    int end = (c < NCRYS - 1) ? crys[(c + 1) * 2] : NN;  // searchsorted boundary
    int len = end - start;
    int per = (len + 63) / 64;
    int s0 = start + chunk * per;
    int e0 = min(s0 + per, end);
    float acc = 0.f;
    for (int i = s0; i < e0; i++)
        acc += (f < 64) ? Hb[(size_t)i * 64 + f] : Ha[(size_t)i * 64 + (f - 64)];
    atomicAdd(&pooled[c * 128 + f], acc);
}

// ============================================================
// Final FC: one wave per (crystal, class)
// ============================================================
__global__ void final2(const float* __restrict__ pooled, const int* __restrict__ crys,
                       const float* __restrict__ fcW, const float* __restrict__ fcb,
                       float* __restrict__ out) {
    int c = blockIdx.x >> 1, o = blockIdx.x & 1;
    int l = threadIdx.x;  // 0..63
    float cnt = (float)(crys[c * 2 + 1] - crys[c * 2]);
    float a = pooled[c * 128 + l] * fcW[l * 2 + o] + pooled[c * 128 + 64 + l] * fcW[(64 + l) * 2 + o];
    for (int s = 32; s > 0; s >>= 1) a += __shfl_down(a, s);
    if (l == 0) out[c * 2 + o] = a / cnt + fcb[o];
}

extern "C" void kernel_launch(void* const* d_in, const int* in_sizes, int n_in,
                              void* d_out, int out_size, void* d_ws, size_t ws_size,
                              hipStream_t stream) {
    const float* bond    = (const float*)d_in[0];
    const float* angle   = (const float*)d_in[1];
    const int*   species = (const int*)d_in[2];
    const int*   nbr     = (const int*)d_in[3];
    const int*   crys    = (const int*)d_in[4];
    const float* W1b_rel = (const float*)d_in[5];
    const float* W1b_root= (const float*)d_in[6];
    const float* b1b     = (const float*)d_in[7];
    const float* W1a_rel = (const float*)d_in[8];
    const float* W1a_root= (const float*)d_in[9];
    const float* b1a     = (const float*)d_in[10];
    const float* W2b_rel = (const float*)d_in[11];
    const float* W2b_root= (const float*)d_in[12];
    const float* b2b     = (const float*)d_in[13];
    const float* W2a_rel = (const float*)d_in[14];
    const float* W2a_root= (const float*)d_in[15];
    const float* b2a     = (const float*)d_in[16];
    const float* fcW     = (const float*)d_in[17];
    const float* fcb     = (const float*)d_in[18];
    float* out = (float*)d_out;

    char* ws = (char*)d_ws;
    size_t off = 0;
    auto alloc = [&](size_t bytes) {
        char* p = ws + off;
        off = (off + bytes + 255) & ~(size_t)255;
        return p;
    };
    __bf16* Wp1b = (__bf16*)alloc((size_t)480 * 256 * 2);
    __bf16* Wp1a = (__bf16*)alloc((size_t)2880 * 256 * 2);
    __bf16* Wp2b = (__bf16*)alloc((size_t)64 * 256 * 2);
    __bf16* Wp2a = (__bf16*)alloc((size_t)64 * 256 * 2);
    float*  Y    = (float*)alloc((size_t)NN * 256 * 4);
    __bf16* Hbp  = (__bf16*)alloc((size_t)2 * MT2 * 512 * 2);
    __bf16* Hap  = (__bf16*)alloc((size_t)2 * MT2 * 512 * 2);
    float*  Hb2  = (float*)alloc((size_t)NN * 64 * 4);
    float*  Ha2  = (float*)alloc((size_t)NN * 64 * 4);
    int*    adj  = (int*)alloc((size_t)NN * 64 * 4);
    int*    deg  = (int*)alloc((size_t)NN * 4);
    float*  pooled = (float*)alloc((size_t)NCRYS * 128 * 4);

    hipMemsetAsync(deg, 0, (size_t)NN * 4, stream);
    hipMemsetAsync(pooled, 0, (size_t)NCRYS * 128 * 4, stream);

    pack_w<<<256, 256, 0, stream>>>(W1b_rel, W1b_root, Wp1b, 480);
    pack_w<<<512, 256, 0, stream>>>(W1a_rel, W1a_root, Wp1a, 2880);
    pack_w<<<32, 256, 0, stream>>>(W2b_rel, W2b_root, Wp2b, 64);
    pack_w<<<32, 256, 0, stream>>>(W2a_rel, W2a_root, Wp2a, 64);
    build_adj_kernel<<<(NN * NEIGH + 255) / 256, 256, 0, stream>>>(species, nbr, adj, deg);

    dim3 gg(157, 2, 1);
    // layer 1 + 2, bond chain
    gemm_mfma<0, 480><<<gg, 256, 0, stream>>>(bond, nullptr, Wp1b, Y);
    agg2<1><<<20096 / 4, 256, 0, stream>>>(Y, adj, deg, b1b, Hbp);
    gemm_mfma<2, 64><<<gg, 256, 0, stream>>>(nullptr, Hbp, Wp2b, Y);
    agg2<0><<<NN / 4, 256, 0, stream>>>(Y, adj, deg, b2b, Hb2);
    // layer 1 + 2, angle chain
    gemm_mfma<1, 2880><<<gg, 256, 0, stream>>>(angle, nullptr, Wp1a, Y);
    agg2<1><<<20096 / 4, 256, 0, stream>>>(Y, adj, deg, b1a, Hap);
    gemm_mfma<2, 64><<<gg, 256, 0, stream>>>(nullptr, Hap, Wp2a, Y);
    agg2<0><<<NN / 4, 256, 0, stream>>>(Y, adj, deg, b2a, Ha2);

    pool_kernel<<<NCRYS * 64, 128, 0, stream>>>(Hb2, Ha2, crys, pooled);
    final2<<<NCRYS * 2, 64, 0, stream>>>(pooled, crys, fcW, fcb, out);
}

// Round 3
// 364.434 us; speedup vs baseline: 2.4262x; 1.0460x over previous
//
#include <hip/hip_runtime.h>

#define NN 20000
#define NNP 20096       // padded rows: 157*128
#define NEIGH 12
#define NCRYS 20
#define MT2 1256        // padded M row-tiles of 16

typedef __bf16 bf16x8 __attribute__((ext_vector_type(8)));
typedef float f32x4 __attribute__((ext_vector_type(4)));

// ============================================================
// prep: zero deg + pooled (replaces 2 memsets)
// ============================================================
__global__ void prep_kernel(int* __restrict__ deg, float* __restrict__ pooled) {
    int i = blockIdx.x * 256 + threadIdx.x;
    if (i < NN) deg[i] = 0;
    if (i < NCRYS * 128) pooled[i] = 0.f;
}

// ============================================================
// Reverse adjacency (fixed across layers)
// ============================================================
__global__ void build_adj_kernel(const int* __restrict__ species, const int* __restrict__ nbr,
                                 int* __restrict__ adj, int* __restrict__ deg) {
    int e = blockIdx.x * blockDim.x + threadIdx.x;
    if (e >= NN * NEIGH) return;
    int i = e / NEIGH;
    int d = nbr[e];
    int r = species[i] + species[d];
    int slot = atomicAdd(&deg[d], 1);
    if (slot < 64) adj[(size_t)d * 64 + slot] = i | (r << 28);
}

// ============================================================
// pack all 4 weight sets -> bf16 MFMA-B frag layout
// Wp[kt][nt][k8][ni][j] : kt=k/32, k8=(k%32)/8, j=k%8, nt=n/16, ni=n%16
// ============================================================
__device__ __forceinline__ void pack_one(const float* Wrel, const float* Wroot,
                                         __bf16* Wp, int K, int idx) {
    int k = idx >> 8, n = idx & 255;
    int r = n >> 6, h = n & 63;
    float v = (r < 3) ? Wrel[((size_t)r * K + k) * 64 + h] : Wroot[(size_t)k * 64 + h];
    int kt = k >> 5, k8 = (k >> 3) & 3, j = k & 7, nt = n >> 4, ni = n & 15;
    Wp[((((size_t)kt * 16 + nt) * 4 + ni) * 16) * 0 +  // (kept simple below)
       ((((size_t)kt * 16 + nt) * 4 + k8) * 16 + ni) * 8 + j] = (__bf16)v;
}

__global__ void pack_all(const float* __restrict__ W1b_rel, const float* __restrict__ W1b_root,
                         const float* __restrict__ W1a_rel, const float* __restrict__ W1a_root,
                         const float* __restrict__ W2b_rel, const float* __restrict__ W2b_root,
                         const float* __restrict__ W2a_rel, const float* __restrict__ W2a_root,
                         __bf16* __restrict__ Wp1b, __bf16* __restrict__ Wp1a,
                         __bf16* __restrict__ Wp2b, __bf16* __restrict__ Wp2a) {
    const int S0 = 480 * 256, S1 = S0 + 2880 * 256, S2 = S1 + 64 * 256, S3 = S2 + 64 * 256;
    for (int idx = blockIdx.x * blockDim.x + threadIdx.x; idx < S3;
         idx += gridDim.x * blockDim.x) {
        if (idx < S0)       pack_one(W1b_rel, W1b_root, Wp1b, 480, idx);
        else if (idx < S1)  pack_one(W1a_rel, W1a_root, Wp1a, 2880, idx - S0);
        else if (idx < S2)  pack_one(W2b_rel, W2b_root, Wp2b, 64, idx - S1);
        else                pack_one(W2a_rel, W2a_root, Wp2a, 64, idx - S2);
    }
}

// ============================================================
// Transpose raw features: angleT[144][NNP], bondT[12][NNP] (pad rows -> 0)
// LDS-tiled: coalesced reads AND writes, bank-conflict-free (odd stride)
// ============================================================
__global__ __launch_bounds__(256, 1) void transpose_kernel(const float* __restrict__ bond,
                                                           const float* __restrict__ angle,
                                                           float* __restrict__ bondT,
                                                           float* __restrict__ angleT) {
    __shared__ float ls[128 * 145];
    int b = blockIdx.x;
    if (b < 157) {
        int m0 = b * 128;
        for (int idx = threadIdx.x; idx < 128 * 144; idx += 256) {
            int mm = idx / 144, j = idx - mm * 144;
            int m = m0 + mm;
            ls[mm * 145 + j] = (m < NN) ? angle[(size_t)m * 144 + j] : 0.f;
        }
        __syncthreads();
        for (int idx = threadIdx.x; idx < 144 * 128; idx += 256) {
            int j = idx >> 7, mm = idx & 127;
            angleT[(size_t)j * NNP + m0 + mm] = ls[mm * 145 + j];
        }
    } else {
        int m0 = (b - 157) * 128;
        for (int idx = threadIdx.x; idx < 128 * 12; idx += 256) {
            int mm = idx / 12, j = idx - mm * 12;
            int m = m0 + mm;
            ls[mm * 13 + j] = (m < NN) ? bond[(size_t)m * 12 + j] : 0.f;
        }
        __syncthreads();
        for (int idx = threadIdx.x; idx < 12 * 128; idx += 256) {
            int j = idx >> 7, mm = idx & 127;
            bondT[(size_t)j * NNP + m0 + mm] = ls[mm * 13 + j];
        }
    }
}

// ============================================================
// GEMM body with fused gbf from TRANSPOSED input.
// block tile 128x128, 4 waves each 64x64 (4x4 of 16x16x32 bf16 MFMA)
// ============================================================
template <int MODE>  // 0: bond K=480 DIVN=40; 1: angle K=2880 DIVN=20
__device__ __forceinline__ void gemm_gbf_body(const float* __restrict__ xT,
                                              const __bf16* __restrict__ Wp,
                                              float* __restrict__ Y,
                                              int mb, int nb, __bf16* Al, __bf16* Bl) {
    constexpr int KTOT = (MODE == 0) ? 480 : 2880;
    constexpr int NKT = KTOT / 32;
    constexpr int DIVN = (MODE == 0) ? 40 : 20;
    const float F0 = (MODE == 0) ? 0.f : -1.f;
    const float FS = (MODE == 0) ? (8.f / 39.f) : (2.f / 19.f);
    const float NG = (MODE == 0) ? -25.f : -100.f;
    const int tid = threadIdx.x;
    const int lane = tid & 63, wv = tid >> 6;
    const int m0 = mb * 128;
    const int rw = wv & 1, cw = wv >> 1;
    f32x4 acc[4][4] = {};

    for (int kt = 0; kt < NKT; ++kt) {
        __syncthreads();
        {   // stage B tile (8 KB, pre-packed frag layout)
            const float4* src = (const float4*)(Wp + (((size_t)kt * 16 + nb * 8) << 9));
            float4* dst = (float4*)Bl;
            float4 v0 = src[tid];
            float4 v1 = src[tid + 256];
            dst[tid] = v0;
            dst[tid + 256] = v1;
        }
        // fused gbf staging from transposed input: quarter-coalesced L1-resident loads
#pragma unroll
        for (int c2 = 0; c2 < 2; ++c2) {
            int c = tid + c2 * 256;
            int mt = c >> 6, k8 = (c >> 4) & 3, mi = c & 15;
            int mloc = mt * 16 + mi;
            int kb = kt * 32 + k8 * 8;
            int jrA = kb / DIVN;
            int jrB = (kb + 7) / DIVN;
            float a0 = xT[(size_t)jrA * NNP + m0 + mloc];
            float a1 = (jrB != jrA) ? xT[(size_t)jrB * NNP + m0 + mloc] : a0;
            bf16x8 vals;
#pragma unroll
            for (int j = 0; j < 8; ++j) {
                int k = kb + j;
                int jr = k / DIVN;
                int s = k - jr * DIVN;
                float a = (jr == jrA) ? a0 : a1;
                float d = a - (F0 + (float)s * FS);
                vals[j] = (__bf16)__expf(d * d * NG);
            }
            *(bf16x8*)&Al[(size_t)c << 3] = vals;
        }
        __syncthreads();
        bf16x8 af[4], bfr[4];
        int fro = ((lane >> 4) << 4) + (lane & 15);
#pragma unroll
        for (int t4 = 0; t4 < 4; ++t4) {
            af[t4] = *(const bf16x8*)&Al[((((rw * 4 + t4) << 6) + fro) << 3)];
            bfr[t4] = *(const bf16x8*)&Bl[((((cw * 4 + t4) << 6) + fro) << 3)];
        }
#pragma unroll
        for (int i = 0; i < 4; ++i)
#pragma unroll
            for (int j = 0; j < 4; ++j)
                acc[i][j] = __builtin_amdgcn_mfma_f32_16x16x32_bf16(af[i], bfr[j], acc[i][j], 0, 0, 0);
    }
    // epilogue: C/D layout col=lane&15, row=(lane>>4)*4+reg
    const int n0 = nb * 128 + cw * 64;
    const int mrow0 = m0 + rw * 64 + ((lane >> 4) << 2);
    const int ncol = n0 + (lane & 15);
#pragma unroll
    for (int i = 0; i < 4; ++i)
#pragma unroll
        for (int j = 0; j < 4; ++j)
#pragma unroll
            for (int v = 0; v < 4; ++v) {
                int m = mrow0 + i * 16 + v;
                if (m < NN) Y[(size_t)m * 256 + ncol + j * 16] = acc[i][j][v];
            }
}

// bond blocks bx<157 (short K) + angle blocks bx>=157 -> one big grid, good CU fill
__global__ __launch_bounds__(256) void mega_gemm1(const float* __restrict__ bondT,
                                                  const float* __restrict__ angleT,
                                                  const __bf16* __restrict__ Wp1b,
                                                  const __bf16* __restrict__ Wp1a,
                                                  float* __restrict__ Yb, float* __restrict__ Ya) {
    __shared__ __align__(16) __bf16 Al[4096];
    __shared__ __align__(16) __bf16 Bl[4096];
    int bx = blockIdx.x, nb = blockIdx.y;
    if (bx < 157) gemm_gbf_body<0>(bondT, Wp1b, Yb, bx, nb, Al, Bl);
    else          gemm_gbf_body<1>(angleT, Wp1a, Ya, bx - 157, nb, Al, Bl);
}

// ============================================================
// Dense layer-2 GEMM, both chains in one kernel. K=64 (2 k-tiles), A pre-packed bf16
// ============================================================
__global__ __launch_bounds__(256) void mega_gemm2(const __bf16* __restrict__ Hbp,
                                                  const __bf16* __restrict__ Hap,
                                                  const __bf16* __restrict__ Wp2b,
                                                  const __bf16* __restrict__ Wp2a,
                                                  float* __restrict__ Yb, float* __restrict__ Ya) {
    __shared__ __align__(16) __bf16 Al[4096];
    __shared__ __align__(16) __bf16 Bl[4096];
    const int ch = blockIdx.x & 1;
    const int mb = blockIdx.x >> 1;
    const int nb = blockIdx.y;
    const __bf16* Ap = ch ? Hap : Hbp;
    const __bf16* Wp = ch ? Wp2a : Wp2b;
    float* Y = ch ? Ya : Yb;
    const int tid = threadIdx.x;
    const int lane = tid & 63, wv = tid >> 6;
    const int m0 = mb * 128;
    const int rw = wv & 1, cw = wv >> 1;
    f32x4 acc[4][4] = {};
#pragma unroll
    for (int kt = 0; kt < 2; ++kt) {
        __syncthreads();
        {
            const float4* src = (const float4*)(Wp + (((size_t)kt * 16 + nb * 8) << 9));
            float4* dst = (float4*)Bl;
            float4 v0 = src[tid], v1 = src[tid + 256];
            dst[tid] = v0;
            dst[tid + 256] = v1;
        }
        {
            const float4* src = (const float4*)(Ap + (((size_t)kt * MT2 + mb * 8) << 9));
            float4* dst = (float4*)Al;
            float4 v0 = src[tid], v1 = src[tid + 256];
            dst[tid] = v0;
            dst[tid + 256] = v1;
        }
        __syncthreads();
        bf16x8 af[4], bfr[4];
        int fro = ((lane >> 4) << 4) + (lane & 15);
#pragma unroll
        for (int t4 = 0; t4 < 4; ++t4) {
            af[t4] = *(const bf16x8*)&Al[((((rw * 4 + t4) << 6) + fro) << 3)];
            bfr[t4] = *(const bf16x8*)&Bl[((((cw * 4 + t4) << 6) + fro) << 3)];
        }
#pragma unroll
        for (int i = 0; i < 4; ++i)
#pragma unroll
            for (int j = 0; j < 4; ++j)
                acc[i][j] = __builtin_amdgcn_mfma_f32_16x16x32_bf16(af[i], bfr[j], acc[i][j], 0, 0, 0);
    }
    const int n0 = nb * 128 + cw * 64;
    const int mrow0 = m0 + rw * 64 + ((lane >> 4) << 2);
    const int ncol = n0 + (lane & 15);
#pragma unroll
    for (int i = 0; i < 4; ++i)
#pragma unroll
        for (int j = 0; j < 4; ++j)
#pragma unroll
            for (int v = 0; v < 4; ++v) {
                int m = mrow0 + i * 16 + v;
                if (m < NN) Y[(size_t)m * 256 + ncol + j * 16] = acc[i][j][v];
            }
}

// ============================================================
// Aggregation, both chains via blockIdx.y. One wave per node.
// OUT_PACKED=1: bf16 packed-A frag layout (feeds dense GEMM), covers pad rows
// OUT_PACKED=0: f32 [node][64] (feeds pooling)
// ============================================================
template <int OUT_PACKED>
__global__ __launch_bounds__(256) void agg2(const float* __restrict__ Yb,
                                            const float* __restrict__ Ya,
                                            const int* __restrict__ adj,
                                            const int* __restrict__ deg,
                                            const float* __restrict__ biasb,
                                            const float* __restrict__ biasa,
                                            void* __restrict__ outb, void* __restrict__ outa) {
    const float* Y = blockIdx.y ? Ya : Yb;
    const float* bias = blockIdx.y ? biasa : biasb;
    void* outp = blockIdx.y ? outa : outb;
    int node = blockIdx.x * 4 + (threadIdx.x >> 6);
    int h = threadIdx.x & 63;
    float o = 0.f;
    if (node < NN) {
        int dg = min(deg[node], 64);
        int e = adj[(size_t)node * 64 + h];
        bool val = h < dg;
        int r = e >> 28;
        unsigned long long bl0 = __ballot(val && r == 0);
        unsigned long long bl1 = __ballot(val && r == 1);
        unsigned long long bl2 = __ballot(val && r == 2);
        int c0 = __popcll(bl0), c1 = __popcll(bl1), c2 = __popcll(bl2);
        float s0 = 0.f, s1 = 0.f, s2 = 0.f;
        for (int k = 0; k < dg; k += 4) {
            float v[4];
            int rr[4];
#pragma unroll
            for (int i = 0; i < 4; ++i) {
                int kk = k + i;
                int ek = __shfl(e, kk);
                int src = ek & 0x0FFFFFFF;
                rr[i] = ek >> 28;
                v[i] = (kk < dg) ? Y[(size_t)src * 256 + rr[i] * 64 + h] : 0.f;
            }
#pragma unroll
            for (int i = 0; i < 4; ++i) {
                if (k + i < dg) {
                    if (rr[i] == 0) s0 += v[i];
                    else if (rr[i] == 1) s1 += v[i];
                    else s2 += v[i];
                }
            }
        }
        o = Y[(size_t)node * 256 + 192 + h] + bias[h] +
            s0 / fmaxf((float)c0, 1.f) + s1 / fmaxf((float)c1, 1.f) +
            s2 / fmaxf((float)c2, 1.f);
        o = fmaxf(o, 0.f);
    }
    if constexpr (OUT_PACKED) {
        int mt = node >> 4, mi = node & 15;
        int ktt = h >> 5, k8 = (h >> 3) & 3, j = h & 7;
        ((__bf16*)outp)[((((size_t)ktt * MT2 + mt) * 4 + k8) * 16 + mi) * 8 + j] = (__bf16)o;
    } else {
        if (node < NN) ((float*)outp)[(size_t)node * 64 + h] = o;
    }
}

// ============================================================
// Crystal pooling + final FC
// ============================================================
__global__ void pool_kernel(const float* __restrict__ Hb, const float* __restrict__ Ha,
                            const int* __restrict__ crys, float* __restrict__ pooled) {
    int c = blockIdx.x >> 6;
    int chunk = blockIdx.x & 63;
    int f = threadIdx.x;
    int start = crys[c * 2];
    int end = (c < NCRYS - 1) ? crys[(c + 1) * 2] : NN;
    int len = end - start;
    int per = (len + 63) / 64;
    int s0 = start + chunk * per;
    int e0 = min(s0 + per, end);
    float acc = 0.f;
    for (int i = s0; i < e0; i++)
        acc += (f < 64) ? Hb[(size_t)i * 64 + f] : Ha[(size_t)i * 64 + (f - 64)];
    atomicAdd(&pooled[c * 128 + f], acc);
}

__global__ void final2(const float* __restrict__ pooled, const int* __restrict__ crys,
                       const float* __restrict__ fcW, const float* __restrict__ fcb,
                       float* __restrict__ out) {
    int c = blockIdx.x >> 1, o = blockIdx.x & 1;
    int l = threadIdx.x;
    float cnt = (float)(crys[c * 2 + 1] - crys[c * 2]);
    float a = pooled[c * 128 + l] * fcW[l * 2 + o] + pooled[c * 128 + 64 + l] * fcW[(64 + l) * 2 + o];
    for (int s = 32; s > 0; s >>= 1) a += __shfl_down(a, s);
    if (l == 0) out[c * 2 + o] = a / cnt + fcb[o];
}

extern "C" void kernel_launch(void* const* d_in, const int* in_sizes, int n_in,
                              void* d_out, int out_size, void* d_ws, size_t ws_size,
                              hipStream_t stream) {
    const float* bond    = (const float*)d_in[0];
    const float* angle   = (const float*)d_in[1];
    const int*   species = (const int*)d_in[2];
    const int*   nbr     = (const int*)d_in[3];
    const int*   crys    = (const int*)d_in[4];
    const float* W1b_rel = (const float*)d_in[5];
    const float* W1b_root= (const float*)d_in[6];
    const float* b1b     = (const float*)d_in[7];
    const float* W1a_rel = (const float*)d_in[8];
    const float* W1a_root= (const float*)d_in[9];
    const float* b1a     = (const float*)d_in[10];
    const float* W2b_rel = (const float*)d_in[11];
    const float* W2b_root= (const float*)d_in[12];
    const float* b2b     = (const float*)d_in[13];
    const float* W2a_rel = (const float*)d_in[14];
    const float* W2a_root= (const float*)d_in[15];
    const float* b2a     = (const float*)d_in[16];
    const float* fcW     = (const float*)d_in[17];
    const float* fcb     = (const float*)d_in[18];
    float* out = (float*)d_out;

    char* ws = (char*)d_ws;
    size_t off = 0;
    auto alloc = [&](size_t bytes) {
        char* p = ws + off;
        off = (off + bytes + 255) & ~(size_t)255;
        return p;
    };
    __bf16* Wp1b = (__bf16*)alloc((size_t)480 * 256 * 2);
    __bf16* Wp1a = (__bf16*)alloc((size_t)2880 * 256 * 2);
    __bf16* Wp2b = (__bf16*)alloc((size_t)64 * 256 * 2);
    __bf16* Wp2a = (__bf16*)alloc((size_t)64 * 256 * 2);
    float*  bondT = (float*)alloc((size_t)12 * NNP * 4);
    float*  angleT= (float*)alloc((size_t)144 * NNP * 4);
    float*  Yb   = (float*)alloc((size_t)NN * 256 * 4);
    float*  Ya   = (float*)alloc((size_t)NN * 256 * 4);
    __bf16* Hbp  = (__bf16*)alloc((size_t)2 * MT2 * 512 * 2);
    __bf16* Hap  = (__bf16*)alloc((size_t)2 * MT2 * 512 * 2);
    float*  Hb2  = (float*)alloc((size_t)NN * 64 * 4);
    float*  Ha2  = (float*)alloc((size_t)NN * 64 * 4);
    int*    adj  = (int*)alloc((size_t)NN * 64 * 4);
    int*    deg  = (int*)alloc((size_t)NN * 4);
    float*  pooled = (float*)alloc((size_t)NCRYS * 128 * 4);

    prep_kernel<<<(NN + 255) / 256, 256, 0, stream>>>(deg, pooled);
    build_adj_kernel<<<(NN * NEIGH + 255) / 256, 256, 0, stream>>>(species, nbr, adj, deg);
    pack_all<<<512, 256, 0, stream>>>(W1b_rel, W1b_root, W1a_rel, W1a_root,
                                      W2b_rel, W2b_root, W2a_rel, W2a_root,
                                      Wp1b, Wp1a, Wp2b, Wp2a);
    transpose_kernel<<<314, 256, 0, stream>>>(bond, angle, bondT, angleT);

    mega_gemm1<<<dim3(314, 2), 256, 0, stream>>>(bondT, angleT, Wp1b, Wp1a, Yb, Ya);
    agg2<1><<<dim3(5024, 2), 256, 0, stream>>>(Yb, Ya, adj, deg, b1b, b1a, Hbp, Hap);
    mega_gemm2<<<dim3(314, 2), 256, 0, stream>>>(Hbp, Hap, Wp2b, Wp2a, Yb, Ya);
    agg2<0><<<dim3(5000, 2), 256, 0, stream>>>(Yb, Ya, adj, deg, b2b, b2a, Hb2, Ha2);

    pool_kernel<<<NCRYS * 64, 128, 0, stream>>>(Hb2, Ha2, crys, pooled);
    final2<<<NCRYS * 2, 64, 0, stream>>>(pooled, crys, fcW, fcb, out);
}

// Round 4
// 310.192 us; speedup vs baseline: 2.8504x; 1.1749x over previous
//
#include <hip/hip_runtime.h>

#define NN 20000
#define NNP 20096       // padded rows: 314*64
#define NEIGH 12
#define NCRYS 20
#define MT2 1256        // padded M row-tiles of 16

typedef __bf16 bf16x8 __attribute__((ext_vector_type(8)));
typedef float f32x4 __attribute__((ext_vector_type(4)));

// ============================================================
// prep: zero deg + pooled
// ============================================================
__global__ void prep_kernel(int* __restrict__ deg, float* __restrict__ pooled) {
    int i = blockIdx.x * 256 + threadIdx.x;
    if (i < NN) deg[i] = 0;
    if (i < NCRYS * 128) pooled[i] = 0.f;
}

// ============================================================
// Reverse adjacency (fixed across layers)
// ============================================================
__global__ void build_adj_kernel(const int* __restrict__ species, const int* __restrict__ nbr,
                                 int* __restrict__ adj, int* __restrict__ deg) {
    int e = blockIdx.x * blockDim.x + threadIdx.x;
    if (e >= NN * NEIGH) return;
    int i = e / NEIGH;
    int d = nbr[e];
    int r = species[i] + species[d];
    int slot = atomicAdd(&deg[d], 1);
    if (slot < 64) adj[(size_t)d * 64 + slot] = i | (r << 28);
}

// ============================================================
// pack all 4 weight sets -> bf16 MFMA-B frag layout
// Wp[kt][nt][k8][ni][j] : kt=k/32, k8=(k%32)/8, j=k%8, nt=n/16, ni=n%16
// ============================================================
__device__ __forceinline__ void pack_one(const float* Wrel, const float* Wroot,
                                         __bf16* Wp, int K, int idx) {
    int k = idx >> 8, n = idx & 255;
    int r = n >> 6, h = n & 63;
    float v = (r < 3) ? Wrel[((size_t)r * K + k) * 64 + h] : Wroot[(size_t)k * 64 + h];
    int kt = k >> 5, k8 = (k >> 3) & 3, j = k & 7, nt = n >> 4, ni = n & 15;
    Wp[((((size_t)kt * 16 + nt) * 4 + k8) * 16 + ni) * 8 + j] = (__bf16)v;
}

__global__ void pack_all(const float* __restrict__ W1b_rel, const float* __restrict__ W1b_root,
                         const float* __restrict__ W1a_rel, const float* __restrict__ W1a_root,
                         const float* __restrict__ W2b_rel, const float* __restrict__ W2b_root,
                         const float* __restrict__ W2a_rel, const float* __restrict__ W2a_root,
                         __bf16* __restrict__ Wp1b, __bf16* __restrict__ Wp1a,
                         __bf16* __restrict__ Wp2b, __bf16* __restrict__ Wp2a) {
    const int S0 = 480 * 256, S1 = S0 + 2880 * 256, S2 = S1 + 64 * 256, S3 = S2 + 64 * 256;
    for (int idx = blockIdx.x * blockDim.x + threadIdx.x; idx < S3;
         idx += gridDim.x * blockDim.x) {
        if (idx < S0)       pack_one(W1b_rel, W1b_root, Wp1b, 480, idx);
        else if (idx < S1)  pack_one(W1a_rel, W1a_root, Wp1a, 2880, idx - S0);
        else if (idx < S2)  pack_one(W2b_rel, W2b_root, Wp2b, 64, idx - S1);
        else                pack_one(W2a_rel, W2a_root, Wp2a, 64, idx - S2);
    }
}

// ============================================================
// Transpose raw features: angleT[144][NNP], bondT[12][NNP] (pad rows -> 0)
// ============================================================
__global__ __launch_bounds__(256, 1) void transpose_kernel(const float* __restrict__ bond,
                                                           const float* __restrict__ angle,
                                                           float* __restrict__ bondT,
                                                           float* __restrict__ angleT) {
    __shared__ float ls[128 * 145];
    int b = blockIdx.x;
    if (b < 157) {
        int m0 = b * 128;
        for (int idx = threadIdx.x; idx < 128 * 144; idx += 256) {
            int mm = idx / 144, j = idx - mm * 144;
            int m = m0 + mm;
            ls[mm * 145 + j] = (m < NN) ? angle[(size_t)m * 144 + j] : 0.f;
        }
        __syncthreads();
        for (int idx = threadIdx.x; idx < 144 * 128; idx += 256) {
            int j = idx >> 7, mm = idx & 127;
            angleT[(size_t)j * NNP + m0 + mm] = ls[mm * 145 + j];
        }
    } else {
        int m0 = (b - 157) * 128;
        for (int idx = threadIdx.x; idx < 128 * 12; idx += 256) {
            int mm = idx / 12, j = idx - mm * 12;
            int m = m0 + mm;
            ls[mm * 13 + j] = (m < NN) ? bond[(size_t)m * 12 + j] : 0.f;
        }
        __syncthreads();
        for (int idx = threadIdx.x; idx < 12 * 128; idx += 256) {
            int j = idx >> 7, mm = idx & 127;
            bondT[(size_t)j * NNP + m0 + mm] = ls[mm * 13 + j];
        }
    }
}

// ============================================================
// Fused gbf A-tile staging: thread's 8-element chunk, exp via v_exp_f32
// ============================================================
template <int MODE>  // 0: bond DIVN=40; 1: angle DIVN=20
__device__ __forceinline__ void stage_A(float a0, float a1, int kt, int k8, int tid,
                                        __bf16* __restrict__ An) {
    constexpr int DIVN = (MODE == 0) ? 40 : 20;
    constexpr float F0 = (MODE == 0) ? 0.f : -1.f;
    constexpr float FS = (MODE == 0) ? (8.f / 39.f) : (2.f / 19.f);
    constexpr float NG2 = ((MODE == 0) ? -25.f : -100.f) * 1.44269504f;  // *log2e
    int kb = kt * 32 + k8 * 8;
    int jr0 = kb / DIVN;
    int s0 = kb - jr0 * DIVN;
    float f = F0 + (float)s0 * FS;
    float a = a0;
    bf16x8 vals;
#pragma unroll
    for (int j = 0; j < 8; ++j) {
        if (MODE == 1) {
            bool cross = (s0 + j == DIVN);  // filter-grid wraps to next angle element
            if (cross) { f = F0; a = a1; }  // -> cndmask, no branch
        }
        float d = a - f;
        vals[j] = (__bf16)__builtin_amdgcn_exp2f(d * d * NG2);
        f += FS;
    }
    *(bf16x8*)&An[tid << 3] = vals;
}

// ============================================================
// Fused gbf GEMM, 64x256 tile, single-barrier double-buffered K-loop.
// 4 waves; wave wv owns 64 output cols (all 64 rows). Per kt: 16 MFMA/wave.
// ============================================================
template <int MODE>
__device__ __forceinline__ void gemm1_body(const float* __restrict__ xT,
                                           const __bf16* __restrict__ Wp,
                                           float* __restrict__ Y, int mb,
                                           __bf16* __restrict__ Al, __bf16* __restrict__ Bl) {
    constexpr int KTOT = (MODE == 0) ? 480 : 2880;
    constexpr int NKT = KTOT / 32;
    constexpr int DIVN = (MODE == 0) ? 40 : 20;
    const int tid = threadIdx.x;
    const int lane = tid & 63, wv = tid >> 6;
    const int m0 = mb * 64;
    const int k8 = (tid >> 4) & 3;
    const int mloc = ((tid >> 6) << 4) + (tid & 15);
    const int gm = m0 + mloc;
    const float4* Wp4 = (const float4*)Wp;

    f32x4 acc[4][4] = {};  // [mfrag][nfrag]
    float4 breg[4];
    float a0n, a1n;

    // ---- prologue: tile 0 ----
    {
#pragma unroll
        for (int i = 0; i < 4; ++i) breg[i] = Wp4[tid + i * 256];
        int kb = k8 * 8;
        int jr0 = kb / DIVN, jr1 = (kb + 7) / DIVN;
        a0n = xT[jr0 * NNP + gm];
        a1n = xT[jr1 * NNP + gm];
    }
    stage_A<MODE>(a0n, a1n, 0, k8, tid, Al);
    {
        float4* d4 = (float4*)Bl;
#pragma unroll
        for (int i = 0; i < 4; ++i) d4[tid + i * 256] = breg[i];
    }
    __syncthreads();

    for (int kt = 0; kt < NKT; ++kt) {
        const int buf = kt & 1;
        __bf16* Ab = Al + (buf << 11);
        __bf16* Bb = Bl + (buf << 13);
        __bf16* An = Al + ((buf ^ 1) << 11);
        __bf16* Bn = Bl + ((buf ^ 1) << 13);
        const bool more = (kt + 1 < NKT);
        if (more) {  // prefetch next tile's inputs (independent of MFMA below)
#pragma unroll
            for (int i = 0; i < 4; ++i) breg[i] = Wp4[(size_t)(kt + 1) * 1024 + tid + i * 256];
            int kb = (kt + 1) * 32 + k8 * 8;
            int jr0 = kb / DIVN, jr1 = (kb + 7) / DIVN;
            a0n = xT[jr0 * NNP + gm];
            a1n = xT[jr1 * NNP + gm];
        }
        // ---- MFMA on current buffer ----
        bf16x8 af[4], bfr[4];
        const int fro = ((lane >> 4) << 4) + (lane & 15);
#pragma unroll
        for (int t = 0; t < 4; ++t) {
            af[t] = *(const bf16x8*)&Ab[((t << 6) + fro) << 3];
            bfr[t] = *(const bf16x8*)&Bb[((((wv << 2) + t) << 6) + fro) << 3];
        }
#pragma unroll
        for (int i = 0; i < 4; ++i)
#pragma unroll
            for (int j = 0; j < 4; ++j)
                acc[i][j] = __builtin_amdgcn_mfma_f32_16x16x32_bf16(af[i], bfr[j], acc[i][j], 0, 0, 0);
        // ---- stage next tile (matrix pipe drains MFMAs meanwhile) ----
        if (more) {
            stage_A<MODE>(a0n, a1n, kt + 1, k8, tid, An);
            float4* d4 = (float4*)Bn;
#pragma unroll
            for (int i = 0; i < 4; ++i) d4[tid + i * 256] = breg[i];
        }
        __syncthreads();
    }

    // ---- epilogue: C/D layout col=lane&15, row=(lane>>4)*4+reg ----
    const int mrow0 = m0 + ((lane >> 4) << 2);
    const int ncol = (wv << 6) + (lane & 15);
#pragma unroll
    for (int i = 0; i < 4; ++i)
#pragma unroll
        for (int j = 0; j < 4; ++j)
#pragma unroll
            for (int v = 0; v < 4; ++v) {
                int m = mrow0 + i * 16 + v;
                if (m < NN) Y[(size_t)m * 256 + ncol + j * 16] = acc[i][j][v];
            }
}

// angle blocks first (long, 90 kt), bond blocks last (short, 15 kt) -> tail fill
__global__ __launch_bounds__(256, 3) void mega_gemm1(const float* __restrict__ bondT,
                                                     const float* __restrict__ angleT,
                                                     const __bf16* __restrict__ Wp1b,
                                                     const __bf16* __restrict__ Wp1a,
                                                     float* __restrict__ Yb, float* __restrict__ Ya) {
    __shared__ __align__(16) __bf16 Al[2 * 2048];
    __shared__ __align__(16) __bf16 Bl[2 * 8192];
    int bx = blockIdx.x;
    if (bx < 314) gemm1_body<1>(angleT, Wp1a, Ya, bx, Al, Bl);
    else          gemm1_body<0>(bondT, Wp1b, Yb, bx - 314, Al, Bl);
}

// ============================================================
// Dense layer-2 GEMM, both chains. K=64 (2 k-tiles), A pre-packed bf16
// ============================================================
__global__ __launch_bounds__(256) void mega_gemm2(const __bf16* __restrict__ Hbp,
                                                  const __bf16* __restrict__ Hap,
                                                  const __bf16* __restrict__ Wp2b,
                                                  const __bf16* __restrict__ Wp2a,
                                                  float* __restrict__ Yb, float* __restrict__ Ya) {
    __shared__ __align__(16) __bf16 Al[4096];
    __shared__ __align__(16) __bf16 Bl[4096];
    const int ch = blockIdx.x & 1;
    const int mb = blockIdx.x >> 1;
    const int nb = blockIdx.y;
    const __bf16* Ap = ch ? Hap : Hbp;
    const __bf16* Wp = ch ? Wp2a : Wp2b;
    float* Y = ch ? Ya : Yb;
    const int tid = threadIdx.x;
    const int lane = tid & 63, wv = tid >> 6;
    const int m0 = mb * 128;
    const int rw = wv & 1, cw = wv >> 1;
    f32x4 acc[4][4] = {};
#pragma unroll
    for (int kt = 0; kt < 2; ++kt) {
        __syncthreads();
        {
            const float4* src = (const float4*)(Wp + (((size_t)kt * 16 + nb * 8) << 9));
            float4* dst = (float4*)Bl;
            float4 v0 = src[tid], v1 = src[tid + 256];
            dst[tid] = v0;
            dst[tid + 256] = v1;
        }
        {
            const float4* src = (const float4*)(Ap + (((size_t)kt * MT2 + mb * 8) << 9));
            float4* dst = (float4*)Al;
            float4 v0 = src[tid], v1 = src[tid + 256];
            dst[tid] = v0;
            dst[tid + 256] = v1;
        }
        __syncthreads();
        bf16x8 af[4], bfr[4];
        int fro = ((lane >> 4) << 4) + (lane & 15);
#pragma unroll
        for (int t4 = 0; t4 < 4; ++t4) {
            af[t4] = *(const bf16x8*)&Al[((((rw * 4 + t4) << 6) + fro) << 3)];
            bfr[t4] = *(const bf16x8*)&Bl[((((cw * 4 + t4) << 6) + fro) << 3)];
        }
#pragma unroll
        for (int i = 0; i < 4; ++i)
#pragma unroll
            for (int j = 0; j < 4; ++j)
                acc[i][j] = __builtin_amdgcn_mfma_f32_16x16x32_bf16(af[i], bfr[j], acc[i][j], 0, 0, 0);
    }
    const int n0 = nb * 128 + cw * 64;
    const int mrow0 = m0 + rw * 64 + ((lane >> 4) << 2);
    const int ncol = n0 + (lane & 15);
#pragma unroll
    for (int i = 0; i < 4; ++i)
#pragma unroll
        for (int j = 0; j < 4; ++j)
#pragma unroll
            for (int v = 0; v < 4; ++v) {
                int m = mrow0 + i * 16 + v;
                if (m < NN) Y[(size_t)m * 256 + ncol + j * 16] = acc[i][j][v];
            }
}

// ============================================================
// Aggregation, both chains via blockIdx.y. One wave per node.
// ============================================================
template <int OUT_PACKED>
__global__ __launch_bounds__(256) void agg2(const float* __restrict__ Yb,
                                            const float* __restrict__ Ya,
                                            const int* __restrict__ adj,
                                            const int* __restrict__ deg,
                                            const float* __restrict__ biasb,
                                            const float* __restrict__ biasa,
                                            void* __restrict__ outb, void* __restrict__ outa) {
    const float* Y = blockIdx.y ? Ya : Yb;
    const float* bias = blockIdx.y ? biasa : biasb;
    void* outp = blockIdx.y ? outa : outb;
    int node = blockIdx.x * 4 + (threadIdx.x >> 6);
    int h = threadIdx.x & 63;
    float o = 0.f;
    if (node < NN) {
        int dg = min(deg[node], 64);
        int e = adj[(size_t)node * 64 + h];
        bool val = h < dg;
        int r = e >> 28;
        unsigned long long bl0 = __ballot(val && r == 0);
        unsigned long long bl1 = __ballot(val && r == 1);
        unsigned long long bl2 = __ballot(val && r == 2);
        int c0 = __popcll(bl0), c1 = __popcll(bl1), c2 = __popcll(bl2);
        float s0 = 0.f, s1 = 0.f, s2 = 0.f;
        for (int k = 0; k < dg; k += 4) {
            float v[4];
            int rr[4];
#pragma unroll
            for (int i = 0; i < 4; ++i) {
                int kk = k + i;
                int ek = __shfl(e, kk);
                int src = ek & 0x0FFFFFFF;
                rr[i] = ek >> 28;
                v[i] = (kk < dg) ? Y[(size_t)src * 256 + rr[i] * 64 + h] : 0.f;
            }
#pragma unroll
            for (int i = 0; i < 4; ++i) {
                if (k + i < dg) {
                    if (rr[i] == 0) s0 += v[i];
                    else if (rr[i] == 1) s1 += v[i];
                    else s2 += v[i];
                }
            }
        }
        o = Y[(size_t)node * 256 + 192 + h] + bias[h] +
            s0 / fmaxf((float)c0, 1.f) + s1 / fmaxf((float)c1, 1.f) +
            s2 / fmaxf((float)c2, 1.f);
        o = fmaxf(o, 0.f);
    }
    if constexpr (OUT_PACKED) {
        int mt = node >> 4, mi = node & 15;
        int ktt = h >> 5, k8 = (h >> 3) & 3, j = h & 7;
        ((__bf16*)outp)[((((size_t)ktt * MT2 + mt) * 4 + k8) * 16 + mi) * 8 + j] = (__bf16)o;
    } else {
        if (node < NN) ((float*)outp)[(size_t)node * 64 + h] = o;
    }
}

// ============================================================
// Crystal pooling + final FC
// ============================================================
__global__ void pool_kernel(const float* __restrict__ Hb, const float* __restrict__ Ha,
                            const int* __restrict__ crys, float* __restrict__ pooled) {
    int c = blockIdx.x >> 6;
    int chunk = blockIdx.x & 63;
    int f = threadIdx.x;
    int start = crys[c * 2];
    int end = (c < NCRYS - 1) ? crys[(c + 1) * 2] : NN;
    int len = end - start;
    int per = (len + 63) / 64;
    int s0 = start + chunk * per;
    int e0 = min(s0 + per, end);
    float acc = 0.f;
    for (int i = s0; i < e0; i++)
        acc += (f < 64) ? Hb[(size_t)i * 64 + f] : Ha[(size_t)i * 64 + (f - 64)];
    atomicAdd(&pooled[c * 128 + f], acc);
}

__global__ void final2(const float* __restrict__ pooled, const int* __restrict__ crys,
                       const float* __restrict__ fcW, const float* __restrict__ fcb,
                       float* __restrict__ out) {
    int c = blockIdx.x >> 1, o = blockIdx.x & 1;
    int l = threadIdx.x;
    float cnt = (float)(crys[c * 2 + 1] - crys[c * 2]);
    float a = pooled[c * 128 + l] * fcW[l * 2 + o] + pooled[c * 128 + 64 + l] * fcW[(64 + l) * 2 + o];
    for (int s = 32; s > 0; s >>= 1) a += __shfl_down(a, s);
    if (l == 0) out[c * 2 + o] = a / cnt + fcb[o];
}

extern "C" void kernel_launch(void* const* d_in, const int* in_sizes, int n_in,
                              void* d_out, int out_size, void* d_ws, size_t ws_size,
                              hipStream_t stream) {
    const float* bond    = (const float*)d_in[0];
    const float* angle   = (const float*)d_in[1];
    const int*   species = (const int*)d_in[2];
    const int*   nbr     = (const int*)d_in[3];
    const int*   crys    = (const int*)d_in[4];
    const float* W1b_rel = (const float*)d_in[5];
    const float* W1b_root= (const float*)d_in[6];
    const float* b1b     = (const float*)d_in[7];
    const float* W1a_rel = (const float*)d_in[8];
    const float* W1a_root= (const float*)d_in[9];
    const float* b1a     = (const float*)d_in[10];
    const float* W2b_rel = (const float*)d_in[11];
    const float* W2b_root= (const float*)d_in[12];
    const float* b2b     = (const float*)d_in[13];
    const float* W2a_rel = (const float*)d_in[14];
    const float* W2a_root= (const float*)d_in[15];
    const float* b2a     = (const float*)d_in[16];
    const float* fcW     = (const float*)d_in[17];
    const float* fcb     = (const float*)d_in[18];
    float* out = (float*)d_out;

    char* ws = (char*)d_ws;
    size_t off = 0;
    auto alloc = [&](size_t bytes) {
        char* p = ws + off;
        off = (off + bytes + 255) & ~(size_t)255;
        return p;
    };
    __bf16* Wp1b = (__bf16*)alloc((size_t)480 * 256 * 2);
    __bf16* Wp1a = (__bf16*)alloc((size_t)2880 * 256 * 2);
    __bf16* Wp2b = (__bf16*)alloc((size_t)64 * 256 * 2);
    __bf16* Wp2a = (__bf16*)alloc((size_t)64 * 256 * 2);
    float*  bondT = (float*)alloc((size_t)12 * NNP * 4);
    float*  angleT= (float*)alloc((size_t)144 * NNP * 4);
    float*  Yb   = (float*)alloc((size_t)NN * 256 * 4);
    float*  Ya   = (float*)alloc((size_t)NN * 256 * 4);
    __bf16* Hbp  = (__bf16*)alloc((size_t)2 * MT2 * 512 * 2);
    __bf16* Hap  = (__bf16*)alloc((size_t)2 * MT2 * 512 * 2);
    float*  Hb2  = (float*)alloc((size_t)NN * 64 * 4);
    float*  Ha2  = (float*)alloc((size_t)NN * 64 * 4);
    int*    adj  = (int*)alloc((size_t)NN * 64 * 4);
    int*    deg  = (int*)alloc((size_t)NN * 4);
    float*  pooled = (float*)alloc((size_t)NCRYS * 128 * 4);

    prep_kernel<<<(NN + 255) / 256, 256, 0, stream>>>(deg, pooled);
    build_adj_kernel<<<(NN * NEIGH + 255) / 256, 256, 0, stream>>>(species, nbr, adj, deg);
    pack_all<<<512, 256, 0, stream>>>(W1b_rel, W1b_root, W1a_rel, W1a_root,
                                      W2b_rel, W2b_root, W2a_rel, W2a_root,
                                      Wp1b, Wp1a, Wp2b, Wp2a);
    transpose_kernel<<<314, 256, 0, stream>>>(bond, angle, bondT, angleT);

    mega_gemm1<<<628, 256, 0, stream>>>(bondT, angleT, Wp1b, Wp1a, Yb, Ya);
    agg2<1><<<dim3(5024, 2), 256, 0, stream>>>(Yb, Ya, adj, deg, b1b, b1a, Hbp, Hap);
    mega_gemm2<<<dim3(314, 2), 256, 0, stream>>>(Hbp, Hap, Wp2b, Wp2a, Yb, Ya);
    agg2<0><<<dim3(5000, 2), 256, 0, stream>>>(Yb, Ya, adj, deg, b2b, b2a, Hb2, Ha2);

    pool_kernel<<<NCRYS * 64, 128, 0, stream>>>(Hb2, Ha2, crys, pooled);
    final2<<<NCRYS * 2, 64, 0, stream>>>(pooled, crys, fcW, fcb, out);
}

// Round 5
// 274.648 us; speedup vs baseline: 3.2193x; 1.1294x over previous
//
#include <hip/hip_runtime.h>

#define NN 20000
#define NNP 20096       // padded rows: 314*64
#define NEIGH 12
#define NCRYS 20
#define MT2 1256        // padded M row-tiles of 16
#define NSUB 16         // pooled partial-sum split (atomic contention)

typedef __bf16 bf16x8 __attribute__((ext_vector_type(8)));
typedef float f32x4 __attribute__((ext_vector_type(4)));

// ============================================================
// pack: W[k][n] -> bf16 MFMA-B frag layout Wp[kt][nt][k8][ni][j]
// ============================================================
__device__ __forceinline__ void pack_one(const float* Wrel, const float* Wroot,
                                         __bf16* Wp, int K, int idx) {
    int k = idx >> 8, n = idx & 255;
    int r = n >> 6, h = n & 63;
    float v = (r < 3) ? Wrel[((size_t)r * K + k) * 64 + h] : Wroot[(size_t)k * 64 + h];
    int kt = k >> 5, k8 = (k >> 3) & 3, j = k & 7, nt = n >> 4, ni = n & 15;
    Wp[((((size_t)kt * 16 + nt) * 4 + k8) * 16 + ni) * 8 + j] = (__bf16)v;
}

// ============================================================
// setup: build_adj (938 blocks) + pack (256 blocks, strided) + transpose (628)
// deg must be pre-zeroed (memsetAsync before this kernel).
// ============================================================
__global__ __launch_bounds__(256) void setup_kernel(
    const int* __restrict__ species, const int* __restrict__ nbr,
    int* __restrict__ adj, int* __restrict__ deg,
    const float* __restrict__ W1b_rel, const float* __restrict__ W1b_root,
    const float* __restrict__ W1a_rel, const float* __restrict__ W1a_root,
    const float* __restrict__ W2b_rel, const float* __restrict__ W2b_root,
    const float* __restrict__ W2a_rel, const float* __restrict__ W2a_root,
    __bf16* __restrict__ Wp1b, __bf16* __restrict__ Wp1a,
    __bf16* __restrict__ Wp2b, __bf16* __restrict__ Wp2a,
    const float* __restrict__ bond, const float* __restrict__ angle,
    float* __restrict__ bondT, float* __restrict__ angleT) {
    __shared__ float ls[64 * 145];
    const int bx = blockIdx.x, tid = threadIdx.x;
    if (bx < 938) {
        // ---- reverse adjacency ----
        int e = bx * 256 + tid;
        if (e < NN * NEIGH) {
            int i = e / NEIGH;
            int d = nbr[e];
            int r = species[i] + species[d];
            int slot = atomicAdd(&deg[d], 1);
            if (slot < 64) adj[(size_t)d * 64 + slot] = i | (r << 28);
        }
    } else if (bx < 938 + 256) {
        // ---- weight pack (grid-stride over 256 blocks) ----
        const int S0 = 480 * 256, S1 = S0 + 2880 * 256, S2 = S1 + 64 * 256, S3 = S2 + 64 * 256;
        for (int idx = (bx - 938) * 256 + tid; idx < S3; idx += 256 * 256) {
            if (idx < S0)       pack_one(W1b_rel, W1b_root, Wp1b, 480, idx);
            else if (idx < S1)  pack_one(W1a_rel, W1a_root, Wp1a, 2880, idx - S0);
            else if (idx < S2)  pack_one(W2b_rel, W2b_root, Wp2b, 64, idx - S1);
            else                pack_one(W2a_rel, W2a_root, Wp2a, 64, idx - S2);
        }
    } else {
        // ---- transpose, 64-row tiles ----
        int tb = bx - 1194;
        if (tb < 314) {
            int m0 = tb * 64;
            for (int idx = tid; idx < 64 * 144; idx += 256) {
                int mm = idx / 144, j = idx - mm * 144;
                int m = m0 + mm;
                ls[mm * 145 + j] = (m < NN) ? angle[(size_t)m * 144 + j] : 0.f;
            }
            __syncthreads();
            for (int idx = tid; idx < 144 * 64; idx += 256) {
                int j = idx >> 6, mm = idx & 63;
                angleT[(size_t)j * NNP + m0 + mm] = ls[mm * 145 + j];
            }
        } else {
            int m0 = (tb - 314) * 64;
            for (int idx = tid; idx < 64 * 12; idx += 256) {
                int mm = idx / 12, j = idx - mm * 12;
                int m = m0 + mm;
                ls[mm * 13 + j] = (m < NN) ? bond[(size_t)m * 12 + j] : 0.f;
            }
            __syncthreads();
            for (int idx = tid; idx < 12 * 64; idx += 256) {
                int j = idx >> 6, mm = idx & 63;
                bondT[(size_t)j * NNP + m0 + mm] = ls[mm * 13 + j];
            }
        }
    }
}

// ============================================================
// Fused gbf A-tile staging: thread's 8-element chunk
// ============================================================
template <int MODE>  // 0: bond DIVN=40; 1: angle DIVN=20
__device__ __forceinline__ void stage_A(float a0, float a1, int kt, int k8, int tid,
                                        __bf16* __restrict__ An) {
    constexpr int DIVN = (MODE == 0) ? 40 : 20;
    constexpr float F0 = (MODE == 0) ? 0.f : -1.f;
    constexpr float FS = (MODE == 0) ? (8.f / 39.f) : (2.f / 19.f);
    constexpr float NG2 = ((MODE == 0) ? -25.f : -100.f) * 1.44269504f;  // *log2e
    int kb = kt * 32 + k8 * 8;
    int jr0 = kb / DIVN;
    int s0 = kb - jr0 * DIVN;
    float f = F0 + (float)s0 * FS;
    float a = a0;
    bf16x8 vals;
#pragma unroll
    for (int j = 0; j < 8; ++j) {
        if (MODE == 1) {
            bool cross = (s0 + j == DIVN);
            if (cross) { f = F0; a = a1; }
        }
        float d = a - f;
        vals[j] = (__bf16)__builtin_amdgcn_exp2f(d * d * NG2);
        f += FS;
    }
    *(bf16x8*)&An[tid << 3] = vals;
}

// ============================================================
// gemm1: 64x128 tile. A: LDS double-buffer (fused gbf), B: global->frag regs
// (Wp packed layout IS the frag layout). Depth-2 a-prefetch, depth-1 B-prefetch.
// 4 waves, each 64 rows x 32 cols: 8 MFMA/kt, acc[4][2].
// ============================================================
template <int MODE>
__device__ __forceinline__ void gemm1_body(const float* __restrict__ xT,
                                           const __bf16* __restrict__ Wp,
                                           float* __restrict__ Y, int mb, int nb,
                                           __bf16* __restrict__ Al) {
    constexpr int KTOT = (MODE == 0) ? 480 : 2880;
    constexpr int NKT = KTOT / 32;
    constexpr int DIVN = (MODE == 0) ? 40 : 20;
    const int tid = threadIdx.x;
    const int lane = tid & 63, wv = tid >> 6;
    const int m0 = mb * 64;
    // staging role
    const int k8s = (tid >> 4) & 3;
    const int gm = m0 + ((tid >> 6) << 4) + (tid & 15);
    // B frag role
    const int k8b = lane >> 4, nib = lane & 15;
    const int ntg0 = nb * 8 + wv * 2;
    const bf16x8* Bg = (const bf16x8*)Wp;

    f32x4 acc[4][2] = {};
    bf16x8 bcur[2], bnxt[2];
    float a0c, a1c, a0n, a1n;

    auto aaddr = [&](int kt, int which) {
        int kb = kt * 32 + k8s * 8;
        int jr = (which == 0) ? (kb / DIVN) : ((kb + 7) / DIVN);
        return (size_t)jr * NNP + gm;
    };

    // ---- prologue ----
    {
        float p0 = xT[aaddr(0, 0)], p1 = xT[aaddr(0, 1)];
        stage_A<MODE>(p0, p1, 0, k8s, tid, Al);
        bcur[0] = Bg[(((size_t)0 + ntg0 + 0) * 4 + k8b) * 16 + nib];
        bcur[1] = Bg[(((size_t)0 + ntg0 + 1) * 4 + k8b) * 16 + nib];
        int k1 = (NKT > 1) ? 1 : 0;
        a0c = xT[aaddr(k1, 0)];
        a1c = xT[aaddr(k1, 1)];
    }
    __syncthreads();

    for (int kt = 0; kt < NKT; ++kt) {
        __bf16* Ab = Al + ((kt & 1) << 11);
        __bf16* An = Al + (((kt & 1) ^ 1) << 11);
        const int ktb = (kt + 1 < NKT) ? kt + 1 : kt;
        const int kta = (kt + 2 < NKT) ? kt + 2 : NKT - 1;
        // prefetch (covers a full iteration of latency; compiler emits vmcnt(N))
        bnxt[0] = Bg[(((size_t)ktb * 16 + ntg0 + 0) * 4 + k8b) * 16 + nib];
        bnxt[1] = Bg[(((size_t)ktb * 16 + ntg0 + 1) * 4 + k8b) * 16 + nib];
        a0n = xT[aaddr(kta, 0)];
        a1n = xT[aaddr(kta, 1)];
        // A frags from LDS
        bf16x8 af[4];
        const int fro = (k8b << 4) + nib;
#pragma unroll
        for (int t = 0; t < 4; ++t)
            af[t] = *(const bf16x8*)&Ab[((t << 6) + fro) << 3];
#pragma unroll
        for (int i = 0; i < 4; ++i)
#pragma unroll
            for (int j = 0; j < 2; ++j)
                acc[i][j] = __builtin_amdgcn_mfma_f32_16x16x32_bf16(af[i], bcur[j], acc[i][j], 0, 0, 0);
        if (kt + 1 < NKT)
            stage_A<MODE>(a0c, a1c, kt + 1, k8s, tid, An);
        __syncthreads();
        bcur[0] = bnxt[0]; bcur[1] = bnxt[1];
        a0c = a0n; a1c = a1n;
    }

    // ---- epilogue: C/D layout col=lane&15, row=(lane>>4)*4+reg ----
    const int mrow0 = m0 + ((lane >> 4) << 2);
    const int ncol = nb * 128 + (wv << 5) + nib;
#pragma unroll
    for (int i = 0; i < 4; ++i)
#pragma unroll
        for (int j = 0; j < 2; ++j)
#pragma unroll
            for (int v = 0; v < 4; ++v) {
                int m = mrow0 + i * 16 + v;
                if (m < NN) Y[(size_t)m * 256 + ncol + j * 16] = acc[i][j][v];
            }
}

// angle blocks first (90 kt), bond blocks (15 kt) fill the tail
__global__ __launch_bounds__(256, 3) void mega_gemm1(const float* __restrict__ bondT,
                                                     const float* __restrict__ angleT,
                                                     const __bf16* __restrict__ Wp1b,
                                                     const __bf16* __restrict__ Wp1a,
                                                     float* __restrict__ Yb, float* __restrict__ Ya) {
    __shared__ __align__(16) __bf16 Al[2 * 2048];
    int bx = blockIdx.x;
    if (bx < 628) gemm1_body<1>(angleT, Wp1a, Ya, bx >> 1, bx & 1, Al);
    else { int b = bx - 628; gemm1_body<0>(bondT, Wp1b, Yb, b >> 1, b & 1, Al); }
}

// ============================================================
// Dense layer-2 GEMM, both chains. K=64, A pre-packed bf16
// ============================================================
__global__ __launch_bounds__(256) void mega_gemm2(const __bf16* __restrict__ Hbp,
                                                  const __bf16* __restrict__ Hap,
                                                  const __bf16* __restrict__ Wp2b,
                                                  const __bf16* __restrict__ Wp2a,
                                                  float* __restrict__ Yb, float* __restrict__ Ya) {
    __shared__ __align__(16) __bf16 Al[4096];
    __shared__ __align__(16) __bf16 Bl[4096];
    const int ch = blockIdx.x & 1;
    const int mb = blockIdx.x >> 1;
    const int nb = blockIdx.y;
    const __bf16* Ap = ch ? Hap : Hbp;
    const __bf16* Wp = ch ? Wp2a : Wp2b;
    float* Y = ch ? Ya : Yb;
    const int tid = threadIdx.x;
    const int lane = tid & 63, wv = tid >> 6;
    const int m0 = mb * 128;
    const int rw = wv & 1, cw = wv >> 1;
    f32x4 acc[4][4] = {};
#pragma unroll
    for (int kt = 0; kt < 2; ++kt) {
        __syncthreads();
        {
            const float4* src = (const float4*)(Wp + (((size_t)kt * 16 + nb * 8) << 9));
            float4* dst = (float4*)Bl;
            float4 v0 = src[tid], v1 = src[tid + 256];
            dst[tid] = v0;
            dst[tid + 256] = v1;
        }
        {
            const float4* src = (const float4*)(Ap + (((size_t)kt * MT2 + mb * 8) << 9));
            float4* dst = (float4*)Al;
            float4 v0 = src[tid], v1 = src[tid + 256];
            dst[tid] = v0;
            dst[tid + 256] = v1;
        }
        __syncthreads();
        bf16x8 af[4], bfr[4];
        int fro = ((lane >> 4) << 4) + (lane & 15);
#pragma unroll
        for (int t4 = 0; t4 < 4; ++t4) {
            af[t4] = *(const bf16x8*)&Al[((((rw * 4 + t4) << 6) + fro) << 3)];
            bfr[t4] = *(const bf16x8*)&Bl[((((cw * 4 + t4) << 6) + fro) << 3)];
        }
#pragma unroll
        for (int i = 0; i < 4; ++i)
#pragma unroll
            for (int j = 0; j < 4; ++j)
                acc[i][j] = __builtin_amdgcn_mfma_f32_16x16x32_bf16(af[i], bfr[j], acc[i][j], 0, 0, 0);
    }
    const int n0 = nb * 128 + cw * 64;
    const int mrow0 = m0 + rw * 64 + ((lane >> 4) << 2);
    const int ncol = n0 + (lane & 15);
#pragma unroll
    for (int i = 0; i < 4; ++i)
#pragma unroll
        for (int j = 0; j < 4; ++j)
#pragma unroll
            for (int v = 0; v < 4; ++v) {
                int m = mrow0 + i * 16 + v;
                if (m < NN) Y[(size_t)m * 256 + ncol + j * 16] = acc[i][j][v];
            }
}

// ============================================================
// agg core: returns relu(root + b + sum_r mean_r) for (node, h)
// ============================================================
__device__ __forceinline__ float agg_node(const float* __restrict__ Y,
                                          const int* __restrict__ adj,
                                          const int* __restrict__ deg,
                                          const float* __restrict__ bias,
                                          int node, int h) {
    int dg = min(deg[node], 64);
    int e = adj[(size_t)node * 64 + h];
    bool val = h < dg;
    int r = e >> 28;
    unsigned long long bl0 = __ballot(val && r == 0);
    unsigned long long bl1 = __ballot(val && r == 1);
    unsigned long long bl2 = __ballot(val && r == 2);
    int c0 = __popcll(bl0), c1 = __popcll(bl1), c2 = __popcll(bl2);
    float s0 = 0.f, s1 = 0.f, s2 = 0.f;
    for (int k = 0; k < dg; k += 4) {
        float v[4];
        int rr[4];
#pragma unroll
        for (int i = 0; i < 4; ++i) {
            int kk = k + i;
            int ek = __shfl(e, kk);
            int src = ek & 0x0FFFFFFF;
            rr[i] = ek >> 28;
            v[i] = (kk < dg) ? Y[(size_t)src * 256 + rr[i] * 64 + h] : 0.f;
        }
#pragma unroll
        for (int i = 0; i < 4; ++i) {
            if (k + i < dg) {
                if (rr[i] == 0) s0 += v[i];
                else if (rr[i] == 1) s1 += v[i];
                else s2 += v[i];
            }
        }
    }
    float o = Y[(size_t)node * 256 + 192 + h] + bias[h] +
              s0 / fmaxf((float)c0, 1.f) + s1 / fmaxf((float)c1, 1.f) +
              s2 / fmaxf((float)c2, 1.f);
    return fmaxf(o, 0.f);
}

// layer-1 agg: write bf16 packed-A frag layout (feeds mega_gemm2)
__global__ __launch_bounds__(256) void agg_packed(const float* __restrict__ Yb,
                                                  const float* __restrict__ Ya,
                                                  const int* __restrict__ adj,
                                                  const int* __restrict__ deg,
                                                  const float* __restrict__ biasb,
                                                  const float* __restrict__ biasa,
                                                  __bf16* __restrict__ outb,
                                                  __bf16* __restrict__ outa) {
    const float* Y = blockIdx.y ? Ya : Yb;
    const float* bias = blockIdx.y ? biasa : biasb;
    __bf16* outp = blockIdx.y ? outa : outb;
    int node = blockIdx.x * 4 + (threadIdx.x >> 6);
    int h = threadIdx.x & 63;
    float o = (node < NN) ? agg_node(Y, adj, deg, bias, node, h) : 0.f;
    int mt = node >> 4, mi = node & 15;
    int ktt = h >> 5, k8 = (h >> 3) & 3, j = h & 7;
    outp[((((size_t)ktt * MT2 + mt) * 4 + k8) * 16 + mi) * 8 + j] = (__bf16)o;
}

// layer-2 agg fused with crystal pooling (16-way-split atomic partials)
__global__ __launch_bounds__(256) void agg_pool(const float* __restrict__ Yb,
                                                const float* __restrict__ Ya,
                                                const int* __restrict__ adj,
                                                const int* __restrict__ deg,
                                                const float* __restrict__ biasb,
                                                const float* __restrict__ biasa,
                                                const int* __restrict__ crys,
                                                float* __restrict__ pooled) {
    const float* Y = blockIdx.y ? Ya : Yb;
    const float* bias = blockIdx.y ? biasa : biasb;
    const int base = blockIdx.y ? 64 : 0;
    int node = blockIdx.x * 4 + (threadIdx.x >> 6);
    int h = threadIdx.x & 63;
    if (node >= NN) return;
    float o = agg_node(Y, adj, deg, bias, node, h);
    // crystal id = searchsorted(starts, node, 'right') - 1
    int c = 0;
#pragma unroll
    for (int t = 1; t < NCRYS; ++t) c += (node >= crys[t * 2]) ? 1 : 0;
    int sub = blockIdx.x & (NSUB - 1);
    atomicAdd(&pooled[((size_t)c * NSUB + sub) * 128 + base + h], o);
}

// ============================================================
// final: reduce partials, divide by count, FC
// ============================================================
__global__ void final2(const float* __restrict__ pooled, const int* __restrict__ crys,
                       const float* __restrict__ fcW, const float* __restrict__ fcb,
                       float* __restrict__ out) {
    int c = blockIdx.x >> 1, o = blockIdx.x & 1;
    int l = threadIdx.x;  // 0..63
    float cnt = (float)(crys[c * 2 + 1] - crys[c * 2]);
    float sb = 0.f, sa = 0.f;
    for (int s = 0; s < NSUB; ++s) {
        sb += pooled[((size_t)c * NSUB + s) * 128 + l];
        sa += pooled[((size_t)c * NSUB + s) * 128 + 64 + l];
    }
    float a = sb * fcW[l * 2 + o] + sa * fcW[(64 + l) * 2 + o];
    for (int s = 32; s > 0; s >>= 1) a += __shfl_down(a, s);
    if (l == 0) out[c * 2 + o] = a / cnt + fcb[o];
}

extern "C" void kernel_launch(void* const* d_in, const int* in_sizes, int n_in,
                              void* d_out, int out_size, void* d_ws, size_t ws_size,
                              hipStream_t stream) {
    const float* bond    = (const float*)d_in[0];
    const float* angle   = (const float*)d_in[1];
    const int*   species = (const int*)d_in[2];
    const int*   nbr     = (const int*)d_in[3];
    const int*   crys    = (const int*)d_in[4];
    const float* W1b_rel = (const float*)d_in[5];
    const float* W1b_root= (const float*)d_in[6];
    const float* b1b     = (const float*)d_in[7];
    const float* W1a_rel = (const float*)d_in[8];
    const float* W1a_root= (const float*)d_in[9];
    const float* b1a     = (const float*)d_in[10];
    const float* W2b_rel = (const float*)d_in[11];
    const float* W2b_root= (const float*)d_in[12];
    const float* b2b     = (const float*)d_in[13];
    const float* W2a_rel = (const float*)d_in[14];
    const float* W2a_root= (const float*)d_in[15];
    const float* b2a     = (const float*)d_in[16];
    const float* fcW     = (const float*)d_in[17];
    const float* fcb     = (const float*)d_in[18];
    float* out = (float*)d_out;

    char* ws = (char*)d_ws;
    size_t off = 0;
    auto alloc = [&](size_t bytes) {
        char* p = ws + off;
        off = (off + bytes + 255) & ~(size_t)255;
        return p;
    };
    __bf16* Wp1b = (__bf16*)alloc((size_t)480 * 256 * 2);
    __bf16* Wp1a = (__bf16*)alloc((size_t)2880 * 256 * 2);
    __bf16* Wp2b = (__bf16*)alloc((size_t)64 * 256 * 2);
    __bf16* Wp2a = (__bf16*)alloc((size_t)64 * 256 * 2);
    float*  bondT = (float*)alloc((size_t)12 * NNP * 4);
    float*  angleT= (float*)alloc((size_t)144 * NNP * 4);
    float*  Yb   = (float*)alloc((size_t)NN * 256 * 4);
    float*  Ya   = (float*)alloc((size_t)NN * 256 * 4);
    __bf16* Hbp  = (__bf16*)alloc((size_t)2 * MT2 * 512 * 2);
    __bf16* Hap  = (__bf16*)alloc((size_t)2 * MT2 * 512 * 2);
    int*    adj  = (int*)alloc((size_t)NN * 64 * 4);
    int*    deg  = (int*)alloc((size_t)NN * 4);
    float*  pooled = (float*)alloc((size_t)NCRYS * NSUB * 128 * 4);

    hipMemsetAsync(deg, 0, (size_t)NN * 4, stream);
    hipMemsetAsync(pooled, 0, (size_t)NCRYS * NSUB * 128 * 4, stream);

    setup_kernel<<<1822, 256, 0, stream>>>(species, nbr, adj, deg,
                                           W1b_rel, W1b_root, W1a_rel, W1a_root,
                                           W2b_rel, W2b_root, W2a_rel, W2a_root,
                                           Wp1b, Wp1a, Wp2b, Wp2a,
                                           bond, angle, bondT, angleT);

    mega_gemm1<<<1256, 256, 0, stream>>>(bondT, angleT, Wp1b, Wp1a, Yb, Ya);
    agg_packed<<<dim3(5024, 2), 256, 0, stream>>>(Yb, Ya, adj, deg, b1b, b1a, Hbp, Hap);
    mega_gemm2<<<dim3(314, 2), 256, 0, stream>>>(Hbp, Hap, Wp2b, Wp2a, Yb, Ya);
    agg_pool<<<dim3(5000, 2), 256, 0, stream>>>(Yb, Ya, adj, deg, b2b, b2a, crys, pooled);
    final2<<<NCRYS * 2, 64, 0, stream>>>(pooled, crys, fcW, fcb, out);
}